// Round 1
// baseline (557.841 us; speedup 1.0000x reference)
//
#include <hip/hip_runtime.h>
#include <math.h>

// Problem constants (from reference): z (16,64,64,64) f32, codebook (1024,64) f32
#define NB 16
#define NC 64      // channels == embedding dim
#define NH 64
#define NW 64
#define NE 1024    // codebook entries
#define HW (NH * NW)          // 4096
#define NTOT (NB * NC * NH * NW)  // 4194304

// ---------------- kernel 1: cbn[k] = 0.5 * ||e_k||^2 ----------------
__global__ void vq_cbnorm_kernel(const float* __restrict__ cb, float* __restrict__ cbn) {
    int k = blockIdx.x * blockDim.x + threadIdx.x;
    if (k < NE) {
        const float* e = cb + ((size_t)k << 6);
        float s0 = 0.f, s1 = 0.f, s2 = 0.f, s3 = 0.f;
        #pragma unroll
        for (int j = 0; j < NC; j += 4) {
            s0 += e[j + 0] * e[j + 0];
            s1 += e[j + 1] * e[j + 1];
            s2 += e[j + 2] * e[j + 2];
            s3 += e[j + 3] * e[j + 3];
        }
        cbn[k] = 0.5f * ((s0 + s1) + (s2 + s3));
    }
}

// ---------------- kernel 2: main VQ ----------------
// grid: NB*NH blocks (one per (b,h)); block: 256 threads = 4 waves.
// lane (= tid & 63) <-> w  (coalesced strided-channel access)
// wave t scans codebook entries [t*256, t*256+256); merge via LDS.
__launch_bounds__(256)
__global__ void vq_main_kernel(const float* __restrict__ z,
                               const float* __restrict__ cb,
                               const float* __restrict__ cbn,
                               float* __restrict__ out,
                               float* __restrict__ loss) {
    const int bh   = blockIdx.x;
    const int b    = bh >> 6;
    const int h    = bh & 63;
    const int tid  = threadIdx.x;
    const int wave = tid >> 6;
    const int lane = tid & 63;   // = w

    // base of this row's elements in (b,c,h,w) layout
    const size_t zbase = (size_t)b * (NC * HW) + (size_t)h * NW + lane;

    // load z row (64 channels) into VGPRs; coalesced across lanes per c
    float zr[NC];
    #pragma unroll
    for (int j = 0; j < NC; ++j)
        zr[j] = z[zbase + (size_t)j * HW];

    // scan this wave's codebook slice; score = 0.5*||e||^2 - z.e
    float vmin = INFINITY;
    int   vidx = 0;
    const int k0 = wave * (NE / 4);
    for (int k = k0; k < k0 + NE / 4; ++k) {
        const float* __restrict__ e = cb + ((size_t)k << 6);  // wave-uniform -> s_load
        float p0 = 0.f, p1 = 0.f, p2 = 0.f, p3 = 0.f;
        float p4 = 0.f, p5 = 0.f, p6 = 0.f, p7 = 0.f;
        #pragma unroll
        for (int j = 0; j < NC; j += 8) {
            p0 += zr[j + 0] * e[j + 0];
            p1 += zr[j + 1] * e[j + 1];
            p2 += zr[j + 2] * e[j + 2];
            p3 += zr[j + 3] * e[j + 3];
            p4 += zr[j + 4] * e[j + 4];
            p5 += zr[j + 5] * e[j + 5];
            p6 += zr[j + 6] * e[j + 6];
            p7 += zr[j + 7] * e[j + 7];
        }
        float dot = ((p0 + p1) + (p2 + p3)) + ((p4 + p5) + (p6 + p7));
        float score = cbn[k] - dot;
        if (score < vmin) { vmin = score; vidx = k; }  // strict < : first-min tie-break
    }

    // merge the 4 per-wave (min, idx) — k-ranges ascend with wave id, so
    // strict < in wave order preserves jnp.argmin first-index semantics.
    __shared__ float smin[4][64];
    __shared__ int   sidx[4][64];
    smin[wave][lane] = vmin;
    sidx[wave][lane] = vidx;
    __syncthreads();

    float m  = smin[0][lane];
    int   mi = sidx[0][lane];
    #pragma unroll
    for (int t = 1; t < 4; ++t) {
        float mt = smin[t][lane];
        int   it = sidx[t][lane];
        if (mt < m) { m = mt; mi = it; }
    }

    // epilogue: wave t writes channels [t*16, t*16+16); gather codebook rows
    // (per-lane mi, float4 from L2-resident codebook), coalesced stores.
    float lsum = 0.f;
    const size_t obase = zbase;  // same (b,c,h,w) layout for output
    #pragma unroll
    for (int cc = 0; cc < 4; ++cc) {
        const int c = wave * 16 + cc * 4;
        const float4 q4 = *reinterpret_cast<const float4*>(cb + ((size_t)mi << 6) + c);
        out[obase + (size_t)(c + 0) * HW] = q4.x;
        out[obase + (size_t)(c + 1) * HW] = q4.y;
        out[obase + (size_t)(c + 2) * HW] = q4.z;
        out[obase + (size_t)(c + 3) * HW] = q4.w;
        float d0 = q4.x - zr[c + 0];
        float d1 = q4.y - zr[c + 1];
        float d2 = q4.z - zr[c + 2];
        float d3 = q4.w - zr[c + 3];
        lsum += d0 * d0 + d1 * d1 + d2 * d2 + d3 * d3;
    }

    // reduce loss: lanes -> wave, waves -> block, one atomic per block.
    #pragma unroll
    for (int off = 32; off > 0; off >>= 1)
        lsum += __shfl_xor(lsum, off, 64);

    __shared__ float swsum[4];
    if (lane == 0) swsum[wave] = lsum;
    __syncthreads();
    if (tid == 0) {
        float s = (swsum[0] + swsum[1]) + (swsum[2] + swsum[3]);
        // loss = (beta + 1) * mean = 1.25 * sum / NTOT
        atomicAdd(loss, s * (1.25f / (float)NTOT));
    }
}

extern "C" void kernel_launch(void* const* d_in, const int* in_sizes, int n_in,
                              void* d_out, int out_size, void* d_ws, size_t ws_size,
                              hipStream_t stream) {
    const float* z  = (const float*)d_in[0];   // 16*64*64*64 f32
    const float* cb = (const float*)d_in[1];   // 1024*64 f32
    float* out  = (float*)d_out;               // [NTOT] z_q + [1] loss
    float* loss = out + (out_size - 1);
    float* cbn  = (float*)d_ws;                // 1024 floats scratch

    // zero the loss accumulator (d_out is poisoned before every timed call)
    hipMemsetAsync(loss, 0, sizeof(float), stream);

    vq_cbnorm_kernel<<<dim3((NE + 255) / 256), dim3(256), 0, stream>>>(cb, cbn);
    vq_main_kernel<<<dim3(NB * NH), dim3(256), 0, stream>>>(z, cb, cbn, out, loss);
}

// Round 2
// 252.177 us; speedup vs baseline: 2.2121x; 2.2121x over previous
//
#include <hip/hip_runtime.h>
#include <math.h>

// Problem constants (from reference): z (16,64,64,64) f32, codebook (1024,64) f32
#define NB 16
#define NC 64      // channels == embedding dim
#define NH 64
#define NW 64
#define NE 1024    // codebook entries
#define HW (NH * NW)          // 4096
#define NTOT (NB * NC * NH * NW)  // 4194304

// ---------------- kernel 1: cbn[k] = 0.5 * ||e_k||^2 ----------------
__global__ void vq_cbnorm_kernel(const float* __restrict__ cb, float* __restrict__ cbn) {
    int k = blockIdx.x * blockDim.x + threadIdx.x;
    if (k < NE) {
        const float* e = cb + ((size_t)k << 6);
        float s0 = 0.f, s1 = 0.f, s2 = 0.f, s3 = 0.f;
        #pragma unroll
        for (int j = 0; j < NC; j += 4) {
            s0 += e[j + 0] * e[j + 0];
            s1 += e[j + 1] * e[j + 1];
            s2 += e[j + 2] * e[j + 2];
            s3 += e[j + 3] * e[j + 3];
        }
        cbn[k] = 0.5f * ((s0 + s1) + (s2 + s3));
    }
}

// ---------------- kernel 2: main VQ ----------------
// grid: NB*NH blocks (one per (b,h)); block: 256 threads = 4 waves.
// lane (= tid & 63) <-> w  (coalesced strided-channel access)
// wave t scans codebook entries [t*256, t*256+256); merge via LDS.
//
// __launch_bounds__(256, 4): 4 waves/EU -> VGPR cap 128, so zr[64] stays in
// registers (R1: default cap of 56 VGPRs spilled zr -> 16 GB of L2 spill
// reloads -> 520 us L2-bound).
__launch_bounds__(256, 4)
__global__ void vq_main_kernel(const float* __restrict__ z,
                               const float* __restrict__ cb,
                               const float* __restrict__ cbn,
                               float* __restrict__ out,
                               float* __restrict__ loss) {
    const int bh   = blockIdx.x;
    const int b    = bh >> 6;
    const int h    = bh & 63;
    const int tid  = threadIdx.x;
    const int wave = tid >> 6;
    const int lane = tid & 63;   // = w

    // base of this row's elements in (b,c,h,w) layout
    const size_t zbase = (size_t)b * (NC * HW) + (size_t)h * NW + lane;

    // load z row (64 channels) into VGPRs; coalesced across lanes per c
    float zr[NC];
    #pragma unroll
    for (int j = 0; j < NC; ++j)
        zr[j] = z[zbase + (size_t)j * HW];

    // scan this wave's codebook slice; score = 0.5*||e||^2 - z.e
    // readfirstlane makes the slice base provably wave-uniform so the
    // codebook reads go to the scalar pipe (s_load) instead of VMEM.
    float vmin = INFINITY;
    int   vidx = 0;
    const int k0u = __builtin_amdgcn_readfirstlane(wave * (NE / 4));
    for (int kk = 0; kk < NE / 4; ++kk) {
        const int k = k0u + kk;  // scalar
        const float* __restrict__ e = cb + ((size_t)k << 6);  // uniform -> s_load
        float p0 = 0.f, p1 = 0.f, p2 = 0.f, p3 = 0.f;
        float p4 = 0.f, p5 = 0.f, p6 = 0.f, p7 = 0.f;
        #pragma unroll
        for (int j = 0; j < NC; j += 8) {
            p0 += zr[j + 0] * e[j + 0];
            p1 += zr[j + 1] * e[j + 1];
            p2 += zr[j + 2] * e[j + 2];
            p3 += zr[j + 3] * e[j + 3];
            p4 += zr[j + 4] * e[j + 4];
            p5 += zr[j + 5] * e[j + 5];
            p6 += zr[j + 6] * e[j + 6];
            p7 += zr[j + 7] * e[j + 7];
        }
        float dot = ((p0 + p1) + (p2 + p3)) + ((p4 + p5) + (p6 + p7));
        float score = cbn[k] - dot;
        if (score < vmin) { vmin = score; vidx = k; }  // strict < : first-min tie-break
    }

    // merge the 4 per-wave (min, idx) — k-ranges ascend with wave id, so
    // strict < in wave order preserves jnp.argmin first-index semantics.
    __shared__ float smin[4][64];
    __shared__ int   sidx[4][64];
    smin[wave][lane] = vmin;
    sidx[wave][lane] = vidx;
    __syncthreads();

    float m  = smin[0][lane];
    int   mi = sidx[0][lane];
    #pragma unroll
    for (int t = 1; t < 4; ++t) {
        float mt = smin[t][lane];
        int   it = sidx[t][lane];
        if (mt < m) { m = mt; mi = it; }
    }

    // epilogue: wave t writes channels [t*16, t*16+16); gather codebook rows
    // (per-lane mi, float4 from L2-resident codebook), coalesced stores.
    float lsum = 0.f;
    const size_t obase = zbase;  // same (b,c,h,w) layout for output
    #pragma unroll
    for (int cc = 0; cc < 4; ++cc) {
        const int c = wave * 16 + cc * 4;
        const float4 q4 = *reinterpret_cast<const float4*>(cb + ((size_t)mi << 6) + c);
        out[obase + (size_t)(c + 0) * HW] = q4.x;
        out[obase + (size_t)(c + 1) * HW] = q4.y;
        out[obase + (size_t)(c + 2) * HW] = q4.z;
        out[obase + (size_t)(c + 3) * HW] = q4.w;
        float d0 = q4.x - zr[c + 0];
        float d1 = q4.y - zr[c + 1];
        float d2 = q4.z - zr[c + 2];
        float d3 = q4.w - zr[c + 3];
        lsum += d0 * d0 + d1 * d1 + d2 * d2 + d3 * d3;
    }

    // reduce loss: lanes -> wave, waves -> block, one atomic per block.
    #pragma unroll
    for (int off = 32; off > 0; off >>= 1)
        lsum += __shfl_xor(lsum, off, 64);

    __shared__ float swsum[4];
    if (lane == 0) swsum[wave] = lsum;
    __syncthreads();
    if (tid == 0) {
        float s = (swsum[0] + swsum[1]) + (swsum[2] + swsum[3]);
        // loss = (beta + 1) * mean = 1.25 * sum / NTOT
        atomicAdd(loss, s * (1.25f / (float)NTOT));
    }
}

extern "C" void kernel_launch(void* const* d_in, const int* in_sizes, int n_in,
                              void* d_out, int out_size, void* d_ws, size_t ws_size,
                              hipStream_t stream) {
    const float* z  = (const float*)d_in[0];   // 16*64*64*64 f32
    const float* cb = (const float*)d_in[1];   // 1024*64 f32
    float* out  = (float*)d_out;               // [NTOT] z_q + [1] loss
    float* loss = out + (out_size - 1);
    float* cbn  = (float*)d_ws;                // 1024 floats scratch

    // zero the loss accumulator (d_out is poisoned before every timed call)
    hipMemsetAsync(loss, 0, sizeof(float), stream);

    vq_cbnorm_kernel<<<dim3((NE + 255) / 256), dim3(256), 0, stream>>>(cb, cbn);
    vq_main_kernel<<<dim3(NB * NH), dim3(256), 0, stream>>>(z, cb, cbn, out, loss);
}

// Round 3
// 232.255 us; speedup vs baseline: 2.4018x; 1.0858x over previous
//
#include <hip/hip_runtime.h>
#include <math.h>

// Problem constants (from reference): z (16,64,64,64) f32, codebook (1024,64) f32
#define NB 16
#define NC 64      // channels == embedding dim
#define NH 64
#define NW 64
#define NE 1024    // codebook entries
#define HW (NH * NW)          // 4096
#define NTOT (NB * NC * NH * NW)  // 4194304

// ---------------- kernel 1: cbn[k] = 0.5 * ||e_k||^2 ----------------
__global__ void vq_cbnorm_kernel(const float* __restrict__ cb, float* __restrict__ cbn) {
    int k = blockIdx.x * blockDim.x + threadIdx.x;
    if (k < NE) {
        const float* e = cb + ((size_t)k << 6);
        float s0 = 0.f, s1 = 0.f, s2 = 0.f, s3 = 0.f;
        #pragma unroll
        for (int j = 0; j < NC; j += 4) {
            s0 += e[j + 0] * e[j + 0];
            s1 += e[j + 1] * e[j + 1];
            s2 += e[j + 2] * e[j + 2];
            s3 += e[j + 3] * e[j + 3];
        }
        cbn[k] = 0.5f * ((s0 + s1) + (s2 + s3));
    }
}

// ---------------- kernel 2: main VQ ----------------
// grid: NB*NH blocks (one per (b,h)); block: 256 threads = 4 waves.
// lane (= tid & 63) <-> w  (coalesced strided-channel access)
// wave t scans codebook entries [t*256, t*256+256); merge via LDS.
//
// R1 lesson: default VGPR budget spilled zr[64] -> L2-bound (520us).
// R2 lesson: zr[wave*16+cc] dynamic index forced zr to scratch ANYWAY
// (VGPR=48, 64MB spill writes). Fix: ALL zr[] accesses compile-time static;
// epilogue iterates all 16 chunks per wave (loss 4x redundant, scaled by 1/4),
// stores gated by wave-uniform predicate.
__launch_bounds__(256, 4)
__global__ void vq_main_kernel(const float* __restrict__ z,
                               const float* __restrict__ cb,
                               const float* __restrict__ cbn,
                               float* __restrict__ out,
                               float* __restrict__ loss) {
    const int bh   = blockIdx.x;
    const int b    = bh >> 6;
    const int h    = bh & 63;
    const int tid  = threadIdx.x;
    const int wave = tid >> 6;
    const int lane = tid & 63;   // = w

    // base of this row's elements in (b,c,h,w) layout
    const size_t zbase = (size_t)b * (NC * HW) + (size_t)h * NW + lane;

    // load z row (64 channels) into VGPRs; coalesced across lanes per c
    float zr[NC];
    #pragma unroll
    for (int j = 0; j < NC; ++j)
        zr[j] = z[zbase + (size_t)j * HW];

    // scan this wave's codebook slice; score = 0.5*||e||^2 - z.e
    // readfirstlane makes the slice base provably wave-uniform so the
    // codebook reads go to the scalar pipe (s_load) instead of VMEM.
    float vmin = INFINITY;
    int   vidx = 0;
    const int k0u = __builtin_amdgcn_readfirstlane(wave * (NE / 4));
    for (int kk = 0; kk < NE / 4; ++kk) {
        const int k = k0u + kk;  // scalar
        const float* __restrict__ e = cb + ((size_t)k << 6);  // uniform -> s_load
        float p0 = 0.f, p1 = 0.f, p2 = 0.f, p3 = 0.f;
        float p4 = 0.f, p5 = 0.f, p6 = 0.f, p7 = 0.f;
        #pragma unroll
        for (int j = 0; j < NC; j += 8) {
            p0 += zr[j + 0] * e[j + 0];
            p1 += zr[j + 1] * e[j + 1];
            p2 += zr[j + 2] * e[j + 2];
            p3 += zr[j + 3] * e[j + 3];
            p4 += zr[j + 4] * e[j + 4];
            p5 += zr[j + 5] * e[j + 5];
            p6 += zr[j + 6] * e[j + 6];
            p7 += zr[j + 7] * e[j + 7];
        }
        float dot = ((p0 + p1) + (p2 + p3)) + ((p4 + p5) + (p6 + p7));
        float score = cbn[k] - dot;
        if (score < vmin) { vmin = score; vidx = k; }  // strict < : first-min tie-break
    }

    // merge the 4 per-wave (min, idx) — k-ranges ascend with wave id, so
    // strict < in wave order preserves jnp.argmin first-index semantics.
    __shared__ float smin[4][64];
    __shared__ int   sidx[4][64];
    smin[wave][lane] = vmin;
    sidx[wave][lane] = vidx;
    __syncthreads();

    float m  = smin[0][lane];
    int   mi = sidx[0][lane];
    #pragma unroll
    for (int t = 1; t < 4; ++t) {
        float mt = smin[t][lane];
        int   it = sidx[t][lane];
        if (mt < m) { m = mt; mi = it; }
    }

    // epilogue: 16 static 4-channel chunks. Every wave computes the full
    // 64-channel loss (static zr indices; 4x redundant -> scale 1/4); only
    // the owning wave stores its quarter (wave-uniform predicate).
    float lsum = 0.f;
    const size_t obase = zbase;  // same (b,c,h,w) layout for output
    const float* __restrict__ qrow = cb + ((size_t)mi << 6);
    #pragma unroll
    for (int cj = 0; cj < 16; ++cj) {
        const int c = cj * 4;  // compile-time constant
        const float4 q4 = *reinterpret_cast<const float4*>(qrow + c);
        float d0 = q4.x - zr[c + 0];
        float d1 = q4.y - zr[c + 1];
        float d2 = q4.z - zr[c + 2];
        float d3 = q4.w - zr[c + 3];
        lsum += d0 * d0 + d1 * d1 + d2 * d2 + d3 * d3;
        if ((cj >> 2) == wave) {  // wave-uniform
            out[obase + (size_t)(c + 0) * HW] = q4.x;
            out[obase + (size_t)(c + 1) * HW] = q4.y;
            out[obase + (size_t)(c + 2) * HW] = q4.z;
            out[obase + (size_t)(c + 3) * HW] = q4.w;
        }
    }

    // reduce loss: lanes -> wave, waves -> block, one atomic per block.
    #pragma unroll
    for (int off = 32; off > 0; off >>= 1)
        lsum += __shfl_xor(lsum, off, 64);

    __shared__ float swsum[4];
    if (lane == 0) swsum[wave] = lsum;
    __syncthreads();
    if (tid == 0) {
        float s = (swsum[0] + swsum[1]) + (swsum[2] + swsum[3]);
        // loss = (beta + 1) * mean; each position's loss counted 4x (once
        // per wave) -> scale 1.25 / (4 * NTOT)
        atomicAdd(loss, s * (1.25f / (4.0f * (float)NTOT)));
    }
}

extern "C" void kernel_launch(void* const* d_in, const int* in_sizes, int n_in,
                              void* d_out, int out_size, void* d_ws, size_t ws_size,
                              hipStream_t stream) {
    const float* z  = (const float*)d_in[0];   // 16*64*64*64 f32
    const float* cb = (const float*)d_in[1];   // 1024*64 f32
    float* out  = (float*)d_out;               // [NTOT] z_q + [1] loss
    float* loss = out + (out_size - 1);
    float* cbn  = (float*)d_ws;                // 1024 floats scratch

    // zero the loss accumulator (d_out is poisoned before every timed call)
    hipMemsetAsync(loss, 0, sizeof(float), stream);

    vq_cbnorm_kernel<<<dim3((NE + 255) / 256), dim3(256), 0, stream>>>(cb, cbn);
    vq_main_kernel<<<dim3(NB * NH), dim3(256), 0, stream>>>(z, cb, cbn, out, loss);
}

// Round 5
// 102.044 us; speedup vs baseline: 5.4667x; 2.2760x over previous
//
#include <hip/hip_runtime.h>
#include <math.h>

// z (16,64,64,64) f32 (b,c,h,w), codebook (1024,64) f32. Out: z_q + loss.
#define NB 16
#define NC 64
#define NH 64
#define NW 64
#define NE 1024
#define HW (NH * NW)              // 4096 = 1<<12
#define CHW (NC * HW)             // 262144 = 1<<18
#define NTOT (NB * NC * NH * NW)  // 4194304
#define NPIX (NB * NH * NW)       // 65536 pixels (rows)

#define ROWS 128                  // pixels per block
#define NBLK (NPIX / ROWS)        // 512 blocks
#define CHUNK 256                 // codebook entries staged per iteration

typedef short bf16x8 __attribute__((ext_vector_type(8)));
typedef float f32x4  __attribute__((ext_vector_type(4)));

// XOR swizzle within a 128-byte row: spreads same-column reads of 8
// consecutive rows across 8 distinct 16B bank-quads (G4 / T2).
__device__ __forceinline__ int swz(int row, int byteoff) {
    return (byteoff ^ ((row & 7) << 4));
}

// fp32 -> bf16 bits, round-to-nearest-even (same as __float2bfloat16;
// self-contained to avoid header dependence).
__device__ __forceinline__ unsigned short bf16bits(float f) {
    union { float f; unsigned u; } cv;
    cv.f = f;
    const unsigned u = cv.u;
    return (unsigned short)((u + 0x7FFFu + ((u >> 16) & 1u)) >> 16);
}

// MFMA-based VQ: scores[pixel][entry] = 0.5*||e||^2 - z.e via bf16 MFMA,
// running argmin in registers, fp32 epilogue for output + loss.
__launch_bounds__(256, 2)
__global__ void vq_mfma_kernel(const float* __restrict__ z,
                               const float* __restrict__ cb,
                               float* __restrict__ out,
                               float* __restrict__ loss) {
    __shared__ __align__(16) short zt[ROWS * 64];      // bf16 z tile, swizzled
    __shared__ __align__(16) short cbb[CHUNK * 64];    // bf16 codebook chunk, swizzled
    __shared__ float cbn_s[CHUNK];                     // 0.5*||e||^2 for chunk
    __shared__ int   rowi[ROWS];                       // per-row argmin
    __shared__ float swsum[4];

    const int tid  = threadIdx.x;
    const int wave = tid >> 6;
    const int lane = tid & 63;
    const int bid  = blockIdx.x;

    // ---- phase 1: stage z tile (fp32 global -> bf16 LDS, swizzled) ----
    // thread t: row = t&127, channel-half = t>>7 (32 channels).
    {
        const int r     = tid & 127;
        const int chalf = tid >> 7;
        const int P     = bid * ROWS + r;          // global pixel
        const int b     = P >> 12;
        const int rem   = P & 4095;                // h*64+w
        const size_t zb = ((size_t)b << 18) + rem;
        #pragma unroll
        for (int q = 0; q < 4; ++q) {
            bf16x8 pk;
            #pragma unroll
            for (int jj = 0; jj < 8; ++jj) {
                const int c = chalf * 32 + q * 8 + jj;
                pk[jj] = (short)bf16bits(z[zb + ((size_t)c << 12)]);
            }
            const int boff = (chalf * 32 + q * 8) * 2;
            *(bf16x8*)((char*)zt + r * 128 + swz(r, boff)) = pk;
        }
    }
    __syncthreads();

    // ---- load A-fragments (this wave's 32 rows, full K=64) ----
    // A layout: lane l -> row (l&15), k = (l>>4)*8 + j  (16x16x32 bf16)
    bf16x8 af[2][2];
    #pragma unroll
    for (int m = 0; m < 2; ++m) {
        const int r = wave * 32 + m * 16 + (lane & 15);
        #pragma unroll
        for (int k0 = 0; k0 < 2; ++k0) {
            const int boff = k0 * 64 + (lane >> 4) * 16;
            af[m][k0] = *(const bf16x8*)((const char*)zt + r * 128 + swz(r, boff));
        }
    }

    float minv[2][4];
    int   mini[2][4];
    #pragma unroll
    for (int m = 0; m < 2; ++m)
        #pragma unroll
        for (int j = 0; j < 4; ++j) { minv[m][j] = INFINITY; mini[m][j] = 0; }

    // ---- phase 2: sweep codebook in chunks of 256 entries ----
    for (int chunk = 0; chunk < NE / CHUNK; ++chunk) {
        // stage chunk: thread t handles entry chunk*256 + t (row t in cbb)
        {
            const int E = chunk * CHUNK + tid;
            const float4* __restrict__ erow = (const float4*)(cb + ((size_t)E << 6));
            float ssq = 0.f;
            #pragma unroll
            for (int q = 0; q < 8; ++q) {
                const float4 a = erow[q * 2 + 0];
                const float4 b4 = erow[q * 2 + 1];
                ssq += a.x * a.x + a.y * a.y + a.z * a.z + a.w * a.w
                     + b4.x * b4.x + b4.y * b4.y + b4.z * b4.z + b4.w * b4.w;
                bf16x8 pk;
                pk[0] = (short)bf16bits(a.x);  pk[1] = (short)bf16bits(a.y);
                pk[2] = (short)bf16bits(a.z);  pk[3] = (short)bf16bits(a.w);
                pk[4] = (short)bf16bits(b4.x); pk[5] = (short)bf16bits(b4.y);
                pk[6] = (short)bf16bits(b4.z); pk[7] = (short)bf16bits(b4.w);
                *(bf16x8*)((char*)cbb + tid * 128 + swz(tid, q * 16)) = pk;
            }
            cbn_s[tid] = 0.5f * ssq;
        }
        __syncthreads();

        // compute: 16 n-tiles of 16 entries each
        #pragma unroll 4
        for (int nt = 0; nt < CHUNK / 16; ++nt) {
            const int el = nt * 16 + (lane & 15);   // local entry (= B col)
            // B layout: lane l -> col (l&15), k = (l>>4)*8 + j
            bf16x8 b0 = *(const bf16x8*)((const char*)cbb + el * 128 + swz(el, 0  + (lane >> 4) * 16));
            bf16x8 b1 = *(const bf16x8*)((const char*)cbb + el * 128 + swz(el, 64 + (lane >> 4) * 16));
            const float cbnl = cbn_s[el];
            const int   idxv = chunk * CHUNK + el;
            #pragma unroll
            for (int m = 0; m < 2; ++m) {
                f32x4 acc = {0.f, 0.f, 0.f, 0.f};
                acc = __builtin_amdgcn_mfma_f32_16x16x32_bf16(af[m][0], b0, acc, 0, 0, 0);
                acc = __builtin_amdgcn_mfma_f32_16x16x32_bf16(af[m][1], b1, acc, 0, 0, 0);
                #pragma unroll
                for (int j = 0; j < 4; ++j) {
                    const float sc = cbnl - acc[j];
                    if (sc < minv[m][j]) { minv[m][j] = sc; mini[m][j] = idxv; }
                }
            }
        }
        __syncthreads();
    }

    // ---- phase 3: cross-lane argmin over the 16 columns per row ----
    // element (m, j, lane): row = wave*32 + m*16 + (lane>>4)*4 + j, col cand.
    #pragma unroll
    for (int m = 0; m < 2; ++m) {
        #pragma unroll
        for (int j = 0; j < 4; ++j) {
            float v = minv[m][j];
            int   i = mini[m][j];
            #pragma unroll
            for (int s = 1; s < 16; s <<= 1) {
                const float ov = __shfl_xor(v, s, 64);
                const int   oi = __shfl_xor(i, s, 64);
                if (ov < v || (ov == v && oi < i)) { v = ov; i = oi; }
            }
            if ((lane & 15) == 0) {
                const int r = wave * 32 + m * 16 + (lane >> 4) * 4 + j;
                rowi[r] = i;
            }
        }
    }
    __syncthreads();

    // ---- phase 4: epilogue — gather fp32 codebook row, store out, loss ----
    float lsum = 0.f;
    {
        const int r     = tid & 127;
        const int chalf = tid >> 7;
        const int P     = bid * ROWS + r;
        const int b     = P >> 12;
        const int rem   = P & 4095;
        const size_t zb = ((size_t)b << 18) + rem;
        const int mi    = rowi[r];
        const float4* __restrict__ qrow = (const float4*)(cb + ((size_t)mi << 6));
        #pragma unroll
        for (int q = 0; q < 8; ++q) {
            const float4 q4 = qrow[chalf * 8 + q];
            const int c = chalf * 32 + q * 4;
            const float z0 = z[zb + ((size_t)(c + 0) << 12)];
            const float z1 = z[zb + ((size_t)(c + 1) << 12)];
            const float z2 = z[zb + ((size_t)(c + 2) << 12)];
            const float z3 = z[zb + ((size_t)(c + 3) << 12)];
            out[zb + ((size_t)(c + 0) << 12)] = q4.x;
            out[zb + ((size_t)(c + 1) << 12)] = q4.y;
            out[zb + ((size_t)(c + 2) << 12)] = q4.z;
            out[zb + ((size_t)(c + 3) << 12)] = q4.w;
            const float d0 = q4.x - z0, d1 = q4.y - z1;
            const float d2 = q4.z - z2, d3 = q4.w - z3;
            lsum += d0 * d0 + d1 * d1 + d2 * d2 + d3 * d3;
        }
    }

    // block loss reduction -> one atomic
    #pragma unroll
    for (int off = 32; off > 0; off >>= 1)
        lsum += __shfl_xor(lsum, off, 64);
    if (lane == 0) swsum[wave] = lsum;
    __syncthreads();
    if (tid == 0) {
        const float s = (swsum[0] + swsum[1]) + (swsum[2] + swsum[3]);
        atomicAdd(loss, s * (1.25f / (float)NTOT));
    }
}

extern "C" void kernel_launch(void* const* d_in, const int* in_sizes, int n_in,
                              void* d_out, int out_size, void* d_ws, size_t ws_size,
                              hipStream_t stream) {
    const float* z  = (const float*)d_in[0];
    const float* cb = (const float*)d_in[1];
    float* out  = (float*)d_out;
    float* loss = out + (out_size - 1);

    (void)hipMemsetAsync(loss, 0, sizeof(float), stream);
    vq_mfma_kernel<<<dim3(NBLK), dim3(256), 0, stream>>>(z, cb, out, loss);
}